// Round 2
// baseline (690.364 us; speedup 1.0000x reference)
//
#include <hip/hip_runtime.h>
#include <cmath>
#include <cstdint>
#include <cstddef>

#define N_NODES 50000
#define N_EDGES 800000
#define EN_TOT  (N_EDGES + N_NODES)   // edges + self loops
#define F1 256                         // HEADS*HID
#define F2 64                          // OUT

__device__ __forceinline__ float bf2f(unsigned short u) {
    return __uint_as_float((unsigned)u << 16);
}
__device__ __forceinline__ unsigned short f2bf(float f) {
    unsigned u = __float_as_uint(f);
    unsigned r = (u + 0x7FFFu + ((u >> 16) & 1u)) >> 16;   // round-nearest-even
    return (unsigned short)r;
}
__device__ __forceinline__ float lrelu(float x) { return x > 0.f ? x : 0.2f * x; }

// ---------------------------------------------------------------- CSR build
__global__ void count_kernel(const int* __restrict__ ei, int* __restrict__ cnt) {
    int e = blockIdx.x * 256 + threadIdx.x;
    if (e >= EN_TOT) return;
    int dst = (e < N_EDGES) ? ei[N_EDGES + e] : (e - N_EDGES);
    atomicAdd(&cnt[dst], 1);
}

// single-block inclusive scan, 1024 threads, 8 elems/thread/pass
__global__ void scan_kernel(const int* __restrict__ cnt, int* __restrict__ rowptr, int n) {
    const int VPT = 8;
    __shared__ int buf[1024];
    __shared__ int carry_s;
    int t = threadIdx.x;
    if (t == 0) { carry_s = 0; rowptr[0] = 0; }
    __syncthreads();
    for (int base = 0; base < n; base += 1024 * VPT) {
        int v[VPT]; int local = 0;
        #pragma unroll
        for (int i = 0; i < VPT; ++i) {
            int idx = base + t * VPT + i;
            v[i] = (idx < n) ? cnt[idx] : 0;
            local += v[i];
        }
        buf[t] = local; __syncthreads();
        for (int off = 1; off < 1024; off <<= 1) {
            int x = (t >= off) ? buf[t - off] : 0;
            __syncthreads();
            buf[t] += x;
            __syncthreads();
        }
        int run = buf[t] - local + carry_s;   // exclusive prefix + carry
        #pragma unroll
        for (int i = 0; i < VPT; ++i) {
            int idx = base + t * VPT + i;
            run += v[i];
            if (idx < n) rowptr[idx + 1] = run;
        }
        __syncthreads();
        if (t == 1023) carry_s += buf[1023];
        __syncthreads();
    }
}

__global__ void fill_kernel(const int* __restrict__ ei, const int* __restrict__ rowptr,
                            int* __restrict__ cursor, int* __restrict__ col) {
    int e = blockIdx.x * 256 + threadIdx.x;
    if (e >= EN_TOT) return;
    int src, dst;
    if (e < N_EDGES) { src = ei[e]; dst = ei[N_EDGES + e]; }
    else             { src = dst = e - N_EDGES; }
    int pos = atomicAdd(&cursor[dst], 1);
    col[rowptr[dst] + pos] = src;
}

// ---------------------------------------------------------------- f32 GEMM
// C[M,N] = A[M,K] @ B[K,N]; 64x64 tile, BK=32, 256 threads, 4x4 micro-tile.
template <int BK>
__global__ void gemm_kernel(const float* __restrict__ A, const float* __restrict__ B,
                            float* __restrict__ C, int M, int N, int K) {
    __shared__ float As[BK][65];
    __shared__ float Bs[BK][65];
    const int tid = threadIdx.x;
    const int tx = tid & 15, ty = tid >> 4;
    const int brow = blockIdx.x * 64, bcol = blockIdx.y * 64;
    float acc[4][4] = {};
    for (int k0 = 0; k0 < K; k0 += BK) {
        #pragma unroll
        for (int i = tid; i < 64 * BK; i += 256) {
            int r = i / BK, c = i % BK;
            int gr = brow + r;
            As[c][r] = (gr < M) ? A[(size_t)gr * K + k0 + c] : 0.f;
        }
        #pragma unroll
        for (int i = tid; i < BK * 64; i += 256) {
            int r = i / 64, c = i % 64;
            Bs[r][c] = B[(size_t)(k0 + r) * N + bcol + c];
        }
        __syncthreads();
        #pragma unroll
        for (int kk = 0; kk < BK; ++kk) {
            float a[4], b[4];
            #pragma unroll
            for (int i = 0; i < 4; ++i) a[i] = As[kk][ty * 4 + i];
            #pragma unroll
            for (int j = 0; j < 4; ++j) b[j] = Bs[kk][tx * 4 + j];
            #pragma unroll
            for (int i = 0; i < 4; ++i)
                #pragma unroll
                for (int j = 0; j < 4; ++j) acc[i][j] += a[i] * b[j];
        }
        __syncthreads();
    }
    #pragma unroll
    for (int i = 0; i < 4; ++i) {
        int r = brow + ty * 4 + i;
        if (r < M) {
            float4 v = make_float4(acc[i][0], acc[i][1], acc[i][2], acc[i][3]);
            *(float4*)&C[(size_t)r * N + bcol + tx * 4] = v;
        }
    }
}

// ------------------------------------------------- per-node attention logits
// layer 1: heads=2, 128 feats each. one wave per node. Also emits bf16 copy of h.
__global__ void alpha1_kernel(const float* __restrict__ h, const float* __restrict__ a_src,
                              const float* __restrict__ a_dst,
                              float* __restrict__ asrc, float* __restrict__ adst,
                              unsigned short* __restrict__ h_bf) {
    int n = blockIdx.x;
    int l = threadIdx.x;                 // 64
    int head = l >> 5;                   // 0..31 -> head0, 32..63 -> head1
    int lf = (l & 31) * 4;
    const float4 hv = *(const float4*)(h + (size_t)n * F1 + head * 128 + lf);
    const float4 as = *(const float4*)(a_src + head * 128 + lf);
    const float4 ad = *(const float4*)(a_dst + head * 128 + lf);

    ushort4 hb;
    hb.x = f2bf(hv.x); hb.y = f2bf(hv.y); hb.z = f2bf(hv.z); hb.w = f2bf(hv.w);
    *(ushort4*)(h_bf + (size_t)n * F1 + head * 128 + lf) = hb;

    float ps = hv.x * as.x + hv.y * as.y + hv.z * as.z + hv.w * as.w;
    float pd = hv.x * ad.x + hv.y * ad.y + hv.z * ad.z + hv.w * ad.w;
    #pragma unroll
    for (int off = 1; off < 32; off <<= 1) {
        ps += __shfl_xor(ps, off);
        pd += __shfl_xor(pd, off);
    }
    if ((l & 31) == 0) {
        asrc[n * 2 + head] = ps;
        adst[n * 2 + head] = pd;
    }
}

// layer 2: 1 head, 64 feats. one wave per node. Also emits bf16 copy of g.
__global__ void alpha2_kernel(const float* __restrict__ g, const float* __restrict__ a_src,
                              const float* __restrict__ a_dst,
                              float* __restrict__ asrc, float* __restrict__ adst,
                              unsigned short* __restrict__ g_bf) {
    int n = blockIdx.x;
    int l = threadIdx.x;                 // 64
    float v = g[(size_t)n * F2 + l];
    g_bf[(size_t)n * F2 + l] = f2bf(v);
    float ps = v * a_src[l];
    float pd = v * a_dst[l];
    #pragma unroll
    for (int off = 1; off < 64; off <<= 1) {
        ps += __shfl_xor(ps, off);
        pd += __shfl_xor(pd, off);
    }
    if (l == 0) { asrc[n] = ps; adst[n] = pd; }
}

// ---------------------------------------------------- layer-1 aggregation
// one block (256 thr = 4 waves) per destination node.
// lane owns feats 4*lane..4*lane+3 (bf16 gather); waves split edges; LDS reduce.
__global__ void agg1_kernel(const unsigned short* __restrict__ h_bf,
                            const float* __restrict__ asrc, const float* __restrict__ adst,
                            const int* __restrict__ rowptr, const int* __restrict__ col,
                            const float* __restrict__ b1, float* __restrict__ h1) {
    int n = blockIdx.x;
    int t = threadIdx.x;
    int lane = t & 63, wave = t >> 6;
    int beg = rowptr[n], end = rowptr[n + 1];
    float ad0 = adst[n * 2 + 0], ad1 = adst[n * 2 + 1];

    // ---- phase 1: online softmax stats, all 256 threads over edges
    float m0 = -INFINITY, s0 = 0.f, m1 = -INFINITY, s1 = 0.f;
    for (int k = beg + t; k < end; k += 256) {
        int src = col[k];
        float e0 = lrelu(asrc[src * 2 + 0] + ad0);
        float e1 = lrelu(asrc[src * 2 + 1] + ad1);
        float nm0 = fmaxf(m0, e0);
        s0 = s0 * expf(m0 - nm0) + expf(e0 - nm0); m0 = nm0;
        float nm1 = fmaxf(m1, e1);
        s1 = s1 * expf(m1 - nm1) + expf(e1 - nm1); m1 = nm1;
    }
    #pragma unroll
    for (int off = 1; off < 64; off <<= 1) {
        float om0 = __shfl_xor(m0, off), os0 = __shfl_xor(s0, off);
        float nm0 = fmaxf(m0, om0);
        s0 = (nm0 == -INFINITY) ? 0.f : (s0 * expf(m0 - nm0) + os0 * expf(om0 - nm0));
        m0 = nm0;
        float om1 = __shfl_xor(m1, off), os1 = __shfl_xor(s1, off);
        float nm1 = fmaxf(m1, om1);
        s1 = (nm1 == -INFINITY) ? 0.f : (s1 * expf(m1 - nm1) + os1 * expf(om1 - nm1));
        m1 = nm1;
    }
    __shared__ float red[4][4];
    __shared__ float fin[4];
    if (lane == 0) { red[wave][0] = m0; red[wave][1] = s0; red[wave][2] = m1; red[wave][3] = s1; }
    __syncthreads();
    if (t == 0) {
        float M0 = -INFINITY, S0 = 0.f, M1 = -INFINITY, S1 = 0.f;
        #pragma unroll
        for (int w = 0; w < 4; ++w) {
            float wm0 = red[w][0], ws0 = red[w][1];
            float nm = fmaxf(M0, wm0);
            S0 = (nm == -INFINITY) ? 0.f : (S0 * expf(M0 - nm) + ws0 * expf(wm0 - nm));
            M0 = nm;
            float wm1 = red[w][2], ws1 = red[w][3];
            float nm1_ = fmaxf(M1, wm1);
            S1 = (nm1_ == -INFINITY) ? 0.f : (S1 * expf(M1 - nm1_) + ws1 * expf(wm1 - nm1_));
            M1 = nm1_;
        }
        fin[0] = M0; fin[1] = 1.f / S0; fin[2] = M1; fin[3] = 1.f / S1;
    }
    __syncthreads();
    float fm0 = fin[0], fi0 = fin[1], fm1 = fin[2], fi1 = fin[3];

    // ---- phase 2: weighted gather, 4 waves over staged edges
    __shared__ int   s_src[64];
    __shared__ float s_al[64][2];
    const int hsel = (lane >= 32) ? 1 : 0;     // head of feats 4*lane..
    float acc0 = 0.f, acc1 = 0.f, acc2 = 0.f, acc3 = 0.f;
    for (int base = beg; base < end; base += 64) {
        int cnt = min(64, end - base);
        __syncthreads();
        if (t < cnt) {
            int src = col[base + t];
            s_src[t] = src;
            float e0 = lrelu(asrc[src * 2 + 0] + ad0);
            float e1 = lrelu(asrc[src * 2 + 1] + ad1);
            s_al[t][0] = expf(e0 - fm0) * fi0;
            s_al[t][1] = expf(e1 - fm1) * fi1;
        }
        __syncthreads();
        for (int i = wave; i < cnt; i += 4) {
            int src = s_src[i];
            float w = s_al[i][hsel];
            ushort4 v = *(const ushort4*)(h_bf + (size_t)src * F1 + lane * 4);
            acc0 += w * bf2f(v.x);
            acc1 += w * bf2f(v.y);
            acc2 += w * bf2f(v.z);
            acc3 += w * bf2f(v.w);
        }
    }
    __shared__ float racc[3][64][4];
    if (wave > 0) {
        racc[wave - 1][lane][0] = acc0; racc[wave - 1][lane][1] = acc1;
        racc[wave - 1][lane][2] = acc2; racc[wave - 1][lane][3] = acc3;
    }
    __syncthreads();
    if (wave == 0) {
        #pragma unroll
        for (int w = 0; w < 3; ++w) {
            acc0 += racc[w][lane][0]; acc1 += racc[w][lane][1];
            acc2 += racc[w][lane][2]; acc3 += racc[w][lane][3];
        }
        const float4 bb = *(const float4*)(b1 + lane * 4);
        float v0 = acc0 + bb.x, v1 = acc1 + bb.y, v2 = acc2 + bb.z, v3 = acc3 + bb.w;
        float4 o;
        o.x = v0 > 0.f ? v0 : expm1f(v0);
        o.y = v1 > 0.f ? v1 : expm1f(v1);
        o.z = v2 > 0.f ? v2 : expm1f(v2);
        o.w = v3 > 0.f ? v3 : expm1f(v3);
        *(float4*)&h1[(size_t)n * F1 + lane * 4] = o;
    }
}

// ---------------------------------------------------- layer-2 aggregation
// one block (256 thr = 4 waves) per node; lane owns feature lane (bf16 gather).
__global__ void agg2_kernel(const unsigned short* __restrict__ g_bf,
                            const float* __restrict__ asrc, const float* __restrict__ adst,
                            const int* __restrict__ rowptr, const int* __restrict__ col,
                            const float* __restrict__ b2, float* __restrict__ out) {
    int n = blockIdx.x;
    int t = threadIdx.x;
    int lane = t & 63, wave = t >> 6;
    int beg = rowptr[n], end = rowptr[n + 1];
    float ad = adst[n];

    float m = -INFINITY, s = 0.f;
    for (int k = beg + t; k < end; k += 256) {
        int src = col[k];
        float e = lrelu(asrc[src] + ad);
        float nm = fmaxf(m, e);
        s = s * expf(m - nm) + expf(e - nm); m = nm;
    }
    #pragma unroll
    for (int off = 1; off < 64; off <<= 1) {
        float om = __shfl_xor(m, off), os = __shfl_xor(s, off);
        float nm = fmaxf(m, om);
        s = (nm == -INFINITY) ? 0.f : (s * expf(m - nm) + os * expf(om - nm));
        m = nm;
    }
    __shared__ float red[4][2];
    __shared__ float fin[2];
    if (lane == 0) { red[wave][0] = m; red[wave][1] = s; }
    __syncthreads();
    if (t == 0) {
        float M = -INFINITY, S = 0.f;
        #pragma unroll
        for (int w = 0; w < 4; ++w) {
            float wm = red[w][0], ws = red[w][1];
            float nm = fmaxf(M, wm);
            S = (nm == -INFINITY) ? 0.f : (S * expf(M - nm) + ws * expf(wm - nm));
            M = nm;
        }
        fin[0] = M; fin[1] = 1.f / S;
    }
    __syncthreads();
    float fm = fin[0], fi = fin[1];

    __shared__ int   s_src[64];
    __shared__ float s_al[64];
    float acc = 0.f;
    for (int base = beg; base < end; base += 64) {
        int cnt = min(64, end - base);
        __syncthreads();
        if (t < cnt) {
            int src = col[base + t];
            s_src[t] = src;
            float e = lrelu(asrc[src] + ad);
            s_al[t] = expf(e - fm) * fi;
        }
        __syncthreads();
        for (int i = wave; i < cnt; i += 4) {
            int src = s_src[i];
            acc += s_al[i] * bf2f(g_bf[(size_t)src * F2 + lane]);
        }
    }
    __shared__ float racc[3][64];
    if (wave > 0) racc[wave - 1][lane] = acc;
    __syncthreads();
    if (wave == 0) {
        #pragma unroll
        for (int w = 0; w < 3; ++w) acc += racc[w][lane];
        out[(size_t)n * F2 + lane] = acc + b2[lane];
    }
}

// ---------------------------------------------------------------- launch
extern "C" void kernel_launch(void* const* d_in, const int* in_sizes, int n_in,
                              void* d_out, int out_size, void* d_ws, size_t ws_size,
                              hipStream_t stream) {
    const float* x      = (const float*)d_in[0];
    const int*   ei     = (const int*)d_in[1];     // [2, E] flat: row0=src, row1=dst
    const float* W1     = (const float*)d_in[2];
    const float* a_src1 = (const float*)d_in[3];
    const float* a_dst1 = (const float*)d_in[4];
    const float* b1     = (const float*)d_in[5];
    const float* W2     = (const float*)d_in[6];
    const float* a_src2 = (const float*)d_in[7];
    const float* a_dst2 = (const float*)d_in[8];
    const float* b2     = (const float*)d_in[9];
    float* out = (float*)d_out;

    char* ws = (char*)d_ws;
    size_t off = 0;
    auto alloc = [&](size_t bytes) -> void* {
        void* p = ws + off;
        off = (off + bytes + 255) & ~(size_t)255;
        return p;
    };
    float* h      = (float*)alloc((size_t)N_NODES * F1 * 4);   // 51.2 MB
    // g and g_bf alias h's region: h is dead after alpha1/agg1, before gemm2.
    float*          g    = (float*)h;                                   // 12.8 MB
    unsigned short* g_bf = (unsigned short*)((char*)h + (16u << 20));   // 6.4 MB @ +16MB
    float* h1     = (float*)alloc((size_t)N_NODES * F1 * 4);   // 51.2 MB
    unsigned short* h_bf = (unsigned short*)alloc((size_t)N_NODES * F1 * 2); // 25.6 MB
    float* asrc1  = (float*)alloc((size_t)N_NODES * 2 * 4);
    float* adst1  = (float*)alloc((size_t)N_NODES * 2 * 4);
    float* asrc2  = (float*)alloc((size_t)N_NODES * 4);
    float* adst2  = (float*)alloc((size_t)N_NODES * 4);
    int*   rowptr = (int*)alloc((size_t)(N_NODES + 1) * 4);
    int*   cnt    = (int*)alloc((size_t)N_NODES * 4);
    int*   cursor = (int*)alloc((size_t)N_NODES * 4);
    int*   col    = (int*)alloc((size_t)EN_TOT * 4);

    hipMemsetAsync(cnt, 0, (size_t)N_NODES * 4, stream);
    hipMemsetAsync(cursor, 0, (size_t)N_NODES * 4, stream);

    const int eb = (EN_TOT + 255) / 256;
    count_kernel<<<eb, 256, 0, stream>>>(ei, cnt);
    scan_kernel<<<1, 1024, 0, stream>>>(cnt, rowptr, N_NODES);
    fill_kernel<<<eb, 256, 0, stream>>>(ei, rowptr, cursor, col);

    const int mb = (N_NODES + 63) / 64;
    gemm_kernel<32><<<dim3(mb, F1 / 64), 256, 0, stream>>>(x, W1, h, N_NODES, F1, 256);
    alpha1_kernel<<<N_NODES, 64, 0, stream>>>(h, a_src1, a_dst1, asrc1, adst1, h_bf);
    agg1_kernel<<<N_NODES, 256, 0, stream>>>(h_bf, asrc1, adst1, rowptr, col, b1, h1);

    gemm_kernel<32><<<dim3(mb, 1), 256, 0, stream>>>(h1, W2, g, N_NODES, F2, 256);
    alpha2_kernel<<<N_NODES, 64, 0, stream>>>(g, a_src2, a_dst2, asrc2, adst2, g_bf);
    agg2_kernel<<<N_NODES, 256, 0, stream>>>(g_bf, asrc2, adst2, rowptr, col, b2, out);
}

// Round 3
// 341.900 us; speedup vs baseline: 2.0192x; 2.0192x over previous
//
#include <hip/hip_runtime.h>
#include <cmath>
#include <cstdint>
#include <cstddef>

#define N_NODES 50000
#define N_EDGES 800000
#define EN_TOT  (N_EDGES + N_NODES)   // edges + self loops
#define F1 256                         // HEADS*HID
#define F2 64                          // OUT

typedef __attribute__((ext_vector_type(8))) short short8;
typedef __attribute__((ext_vector_type(4))) float float4v;

__device__ __forceinline__ float bf2f(unsigned short u) {
    return __uint_as_float((unsigned)u << 16);
}
__device__ __forceinline__ unsigned short f2bf(float f) {
    unsigned u = __float_as_uint(f);
    unsigned r = (u + 0x7FFFu + ((u >> 16) & 1u)) >> 16;   // round-nearest-even
    return (unsigned short)r;
}
__device__ __forceinline__ float lrelu(float x) { return x > 0.f ? x : 0.2f * x; }

// ---------------------------------------------------------------- CSR build
__global__ void count_kernel(const int* __restrict__ ei, int* __restrict__ cnt) {
    int e = blockIdx.x * 256 + threadIdx.x;
    if (e >= EN_TOT) return;
    int dst = (e < N_EDGES) ? ei[N_EDGES + e] : (e - N_EDGES);
    atomicAdd(&cnt[dst], 1);
}

__global__ void scan_kernel(const int* __restrict__ cnt, int* __restrict__ rowptr, int n) {
    const int VPT = 8;
    __shared__ int buf[1024];
    __shared__ int carry_s;
    int t = threadIdx.x;
    if (t == 0) { carry_s = 0; rowptr[0] = 0; }
    __syncthreads();
    for (int base = 0; base < n; base += 1024 * VPT) {
        int v[VPT]; int local = 0;
        #pragma unroll
        for (int i = 0; i < VPT; ++i) {
            int idx = base + t * VPT + i;
            v[i] = (idx < n) ? cnt[idx] : 0;
            local += v[i];
        }
        buf[t] = local; __syncthreads();
        for (int off = 1; off < 1024; off <<= 1) {
            int x = (t >= off) ? buf[t - off] : 0;
            __syncthreads();
            buf[t] += x;
            __syncthreads();
        }
        int run = buf[t] - local + carry_s;
        #pragma unroll
        for (int i = 0; i < VPT; ++i) {
            int idx = base + t * VPT + i;
            run += v[i];
            if (idx < n) rowptr[idx + 1] = run;
        }
        __syncthreads();
        if (t == 1023) carry_s += buf[1023];
        __syncthreads();
    }
}

__global__ void fill_kernel(const int* __restrict__ ei, const int* __restrict__ rowptr,
                            int* __restrict__ cursor, int* __restrict__ col) {
    int e = blockIdx.x * 256 + threadIdx.x;
    if (e >= EN_TOT) return;
    int src, dst;
    if (e < N_EDGES) { src = ei[e]; dst = ei[N_EDGES + e]; }
    else             { src = dst = e - N_EDGES; }
    int pos = atomicAdd(&cursor[dst], 1);
    col[rowptr[dst] + pos] = src;
}

// --------------------------------------------- W -> W^T bf16 (tiny matrices)
__global__ void convWT_kernel(const float* __restrict__ W, unsigned short* __restrict__ Wt,
                              int K, int Nw) {
    int idx = blockIdx.x * 256 + threadIdx.x;
    if (idx >= K * Nw) return;
    int n = idx / K, k = idx % K;
    Wt[idx] = f2bf(W[(size_t)k * Nw + n]);
}

// ---------------------------------------------------------------- MFMA GEMM
// C_bf16[M,N] = A[M,K] @ Wt^T where Wt is [N,K] bf16 row-major.
// A: f32 (converted during staging) or bf16. BK=64, 256 threads.
// LDS tiles XOR-swizzled (byte ^= (row&7)<<4) on both write and read sides.
template <int BM, int BN, int WAVES_M, int WAVES_N, bool A_F32>
__global__ __launch_bounds__(256)
void gemm_bf16(const void* __restrict__ Aptr, const unsigned short* __restrict__ Bt,
               unsigned short* __restrict__ Cbf, int M, int N, int K) {
    constexpr int BK = 64;
    constexpr int FM = BM / (WAVES_M * 16);
    constexpr int FN = BN / (WAVES_N * 16);
    __shared__ short As[BM * BK];
    __shared__ short Bs[BN * BK];
    const int tid = threadIdx.x;
    const int lane = tid & 63, wid = tid >> 6;
    const int wr = wid / WAVES_N, wc = wid % WAVES_N;
    const int RW = wr * FM * 16, CW = wc * FN * 16;
    const int brow = blockIdx.x * BM, bcol = blockIdx.y * BN;
    const int lr = lane & 15, lkg = lane >> 4;

    float4v acc[FM][FN];
    #pragma unroll
    for (int m = 0; m < FM; ++m)
        #pragma unroll
        for (int n = 0; n < FN; ++n) acc[m][n] = (float4v){0.f, 0.f, 0.f, 0.f};

    for (int k0 = 0; k0 < K; k0 += BK) {
        // ---- stage A
        if constexpr (A_F32) {
            const float* A = (const float*)Aptr;
            #pragma unroll
            for (int p = 0; p < BM * BK / 1024; ++p) {
                int flat = (p * 256 + tid) * 4;
                int r = flat / BK, kk = flat % BK;
                int gr = brow + r;
                float4 v = make_float4(0.f, 0.f, 0.f, 0.f);
                if (gr < M) v = *(const float4*)&A[(size_t)gr * K + k0 + kk];
                ushort4 o;
                o.x = f2bf(v.x); o.y = f2bf(v.y); o.z = f2bf(v.z); o.w = f2bf(v.w);
                *(ushort4*)((char*)As + r * (BK * 2) + ((kk * 2) ^ ((r & 7) << 4))) = o;
            }
        } else {
            const unsigned short* A = (const unsigned short*)Aptr;
            #pragma unroll
            for (int p = 0; p < BM * BK / 2048; ++p) {
                int flat = (p * 256 + tid) * 8;
                int r = flat / BK, kk = flat % BK;
                int gr = brow + r;
                short8 v = {0, 0, 0, 0, 0, 0, 0, 0};
                if (gr < M) v = *(const short8*)&A[(size_t)gr * K + k0 + kk];
                *(short8*)((char*)As + r * (BK * 2) + ((kk * 2) ^ ((r & 7) << 4))) = v;
            }
        }
        // ---- stage B (Wt rows = output columns)
        #pragma unroll
        for (int p = 0; p < BN * BK / 2048; ++p) {
            int flat = (p * 256 + tid) * 8;
            int r = flat / BK, kk = flat % BK;
            short8 v = *(const short8*)&Bt[(size_t)(bcol + r) * K + k0 + kk];
            *(short8*)((char*)Bs + r * (BK * 2) + ((kk * 2) ^ ((r & 7) << 4))) = v;
        }
        __syncthreads();
        #pragma unroll
        for (int ks = 0; ks < 2; ++ks) {
            short8 af[FM], bfr[FN];
            #pragma unroll
            for (int m = 0; m < FM; ++m) {
                int row = RW + m * 16 + lr;
                af[m] = *(const short8*)((const char*)As + row * (BK * 2) +
                        (((ks * 32 + lkg * 8) * 2) ^ ((row & 7) << 4)));
            }
            #pragma unroll
            for (int n = 0; n < FN; ++n) {
                int row = CW + n * 16 + lr;
                bfr[n] = *(const short8*)((const char*)Bs + row * (BK * 2) +
                        (((ks * 32 + lkg * 8) * 2) ^ ((row & 7) << 4)));
            }
            #pragma unroll
            for (int m = 0; m < FM; ++m)
                #pragma unroll
                for (int n = 0; n < FN; ++n)
                    acc[m][n] = __builtin_amdgcn_mfma_f32_16x16x32_bf16(
                        af[m], bfr[n], acc[m][n], 0, 0, 0);
        }
        __syncthreads();
    }
    // ---- epilogue: C/D layout col=lane&15, row=(lane>>4)*4+j
    #pragma unroll
    for (int m = 0; m < FM; ++m) {
        #pragma unroll
        for (int j = 0; j < 4; ++j) {
            int row = brow + RW + m * 16 + lkg * 4 + j;
            if (row < M) {
                #pragma unroll
                for (int n = 0; n < FN; ++n) {
                    int c = bcol + CW + n * 16 + lr;
                    Cbf[(size_t)row * N + c] = f2bf(acc[m][n][j]);
                }
            }
        }
    }
}

// ------------------------------------------------- per-node attention logits
// 4 nodes per block (wave per node).
__global__ __launch_bounds__(256)
void alpha1_kernel(const unsigned short* __restrict__ h_bf, const float* __restrict__ a_src,
                   const float* __restrict__ a_dst,
                   float* __restrict__ asrc, float* __restrict__ adst) {
    int n = blockIdx.x * 4 + (threadIdx.x >> 6);
    if (n >= N_NODES) return;
    int lane = threadIdx.x & 63;
    int head = lane >> 5, f = (lane & 31) * 4;
    ushort4 hv = *(const ushort4*)(h_bf + (size_t)n * F1 + head * 128 + f);
    float4 as = *(const float4*)(a_src + head * 128 + f);
    float4 ad = *(const float4*)(a_dst + head * 128 + f);
    float h0 = bf2f(hv.x), h1 = bf2f(hv.y), h2 = bf2f(hv.z), h3 = bf2f(hv.w);
    float ps = h0 * as.x + h1 * as.y + h2 * as.z + h3 * as.w;
    float pd = h0 * ad.x + h1 * ad.y + h2 * ad.z + h3 * ad.w;
    #pragma unroll
    for (int off = 16; off; off >>= 1) {
        ps += __shfl_xor(ps, off);
        pd += __shfl_xor(pd, off);
    }
    if ((lane & 31) == 0) {
        asrc[n * 2 + head] = ps;
        adst[n * 2 + head] = pd;
    }
}

__global__ __launch_bounds__(256)
void alpha2_kernel(const unsigned short* __restrict__ g_bf, const float* __restrict__ a_src,
                   const float* __restrict__ a_dst,
                   float* __restrict__ asrc, float* __restrict__ adst) {
    int n = blockIdx.x * 4 + (threadIdx.x >> 6);
    if (n >= N_NODES) return;
    int lane = threadIdx.x & 63;
    float v = bf2f(g_bf[(size_t)n * F2 + lane]);
    float ps = v * a_src[lane];
    float pd = v * a_dst[lane];
    #pragma unroll
    for (int off = 32; off; off >>= 1) {
        ps += __shfl_xor(ps, off);
        pd += __shfl_xor(pd, off);
    }
    if (lane == 0) { asrc[n] = ps; adst[n] = pd; }
}

// ---------------------------------------------------- layer-1 aggregation
// one WAVE per node (4 nodes/block, no barriers). lane owns feats 4*lane..+3.
// fast path deg<=64: edge-per-lane, exact max/sum via shuffles, weights in regs.
__global__ __launch_bounds__(256)
void agg1_kernel(const unsigned short* __restrict__ h_bf,
                 const float* __restrict__ asrc, const float* __restrict__ adst,
                 const int* __restrict__ rowptr, const int* __restrict__ col,
                 const float* __restrict__ b1, unsigned short* __restrict__ h1_bf) {
    int n = blockIdx.x * 4 + (threadIdx.x >> 6);
    if (n >= N_NODES) return;
    int lane = threadIdx.x & 63;
    int beg = rowptr[n], end = rowptr[n + 1];
    int deg = end - beg;
    float ad0 = adst[2 * n], ad1 = adst[2 * n + 1];
    float a0 = 0.f, a1 = 0.f, a2 = 0.f, a3 = 0.f;

    if (deg <= 64) {
        bool act = lane < deg;
        int src = 0; float e0 = -INFINITY, e1 = -INFINITY;
        if (act) {
            src = col[beg + lane];
            float2 av = *(const float2*)(asrc + 2 * src);
            e0 = lrelu(av.x + ad0); e1 = lrelu(av.y + ad1);
        }
        float m0 = e0, m1 = e1;
        #pragma unroll
        for (int off = 32; off; off >>= 1) {
            m0 = fmaxf(m0, __shfl_xor(m0, off));
            m1 = fmaxf(m1, __shfl_xor(m1, off));
        }
        float p0 = act ? __expf(e0 - m0) : 0.f;
        float p1 = act ? __expf(e1 - m1) : 0.f;
        float s0 = p0, s1 = p1;
        #pragma unroll
        for (int off = 32; off; off >>= 1) {
            s0 += __shfl_xor(s0, off);
            s1 += __shfl_xor(s1, off);
        }
        float w0 = p0 / s0, w1 = p1 / s1;
        for (int i = 0; i < deg; ++i) {
            float wa = __shfl(w0, i), wb = __shfl(w1, i);
            int s = __shfl(src, i);
            float w = (lane >= 32) ? wb : wa;
            ushort4 v = *(const ushort4*)(h_bf + (size_t)s * F1 + lane * 4);
            a0 += w * bf2f(v.x); a1 += w * bf2f(v.y);
            a2 += w * bf2f(v.z); a3 += w * bf2f(v.w);
        }
    } else {
        // general path: two passes, chunks of 64
        float m0 = -INFINITY, s0 = 0.f, m1 = -INFINITY, s1 = 0.f;
        for (int k = beg + lane; k < end; k += 64) {
            int src = col[k];
            float2 av = *(const float2*)(asrc + 2 * src);
            float e0 = lrelu(av.x + ad0), e1 = lrelu(av.y + ad1);
            float nm = fmaxf(m0, e0); s0 = s0 * __expf(m0 - nm) + __expf(e0 - nm); m0 = nm;
            nm = fmaxf(m1, e1); s1 = s1 * __expf(m1 - nm) + __expf(e1 - nm); m1 = nm;
        }
        #pragma unroll
        for (int off = 32; off; off >>= 1) {
            float om = __shfl_xor(m0, off), os = __shfl_xor(s0, off);
            float nm = fmaxf(m0, om);
            s0 = (nm == -INFINITY) ? 0.f : (s0 * __expf(m0 - nm) + os * __expf(om - nm));
            m0 = nm;
            om = __shfl_xor(m1, off); os = __shfl_xor(s1, off);
            nm = fmaxf(m1, om);
            s1 = (nm == -INFINITY) ? 0.f : (s1 * __expf(m1 - nm) + os * __expf(om - nm));
            m1 = nm;
        }
        float i0 = 1.f / s0, i1 = 1.f / s1;
        for (int base = beg; base < end; base += 64) {
            int k = base + lane;
            bool act = k < end;
            int src = 0; float w0 = 0.f, w1 = 0.f;
            if (act) {
                src = col[k];
                float2 av = *(const float2*)(asrc + 2 * src);
                w0 = __expf(lrelu(av.x + ad0) - m0) * i0;
                w1 = __expf(lrelu(av.y + ad1) - m1) * i1;
            }
            int cnt = min(64, end - base);
            for (int i = 0; i < cnt; ++i) {
                float wa = __shfl(w0, i), wb = __shfl(w1, i);
                int s = __shfl(src, i);
                float w = (lane >= 32) ? wb : wa;
                ushort4 v = *(const ushort4*)(h_bf + (size_t)s * F1 + lane * 4);
                a0 += w * bf2f(v.x); a1 += w * bf2f(v.y);
                a2 += w * bf2f(v.z); a3 += w * bf2f(v.w);
            }
        }
    }
    const float4 bb = *(const float4*)(b1 + lane * 4);
    float v0 = a0 + bb.x, v1 = a1 + bb.y, v2 = a2 + bb.z, v3 = a3 + bb.w;
    v0 = v0 > 0.f ? v0 : expm1f(v0);
    v1 = v1 > 0.f ? v1 : expm1f(v1);
    v2 = v2 > 0.f ? v2 : expm1f(v2);
    v3 = v3 > 0.f ? v3 : expm1f(v3);
    ushort4 o; o.x = f2bf(v0); o.y = f2bf(v1); o.z = f2bf(v2); o.w = f2bf(v3);
    *(ushort4*)(h1_bf + (size_t)n * F1 + lane * 4) = o;
}

// ---------------------------------------------------- layer-2 aggregation
// one wave per node; lane owns feature lane. f32 out + b2.
__global__ __launch_bounds__(256)
void agg2_kernel(const unsigned short* __restrict__ g_bf,
                 const float* __restrict__ asrc, const float* __restrict__ adst,
                 const int* __restrict__ rowptr, const int* __restrict__ col,
                 const float* __restrict__ b2, float* __restrict__ out) {
    int n = blockIdx.x * 4 + (threadIdx.x >> 6);
    if (n >= N_NODES) return;
    int lane = threadIdx.x & 63;
    int beg = rowptr[n], end = rowptr[n + 1];
    int deg = end - beg;
    float ad = adst[n];
    float acc = 0.f;

    if (deg <= 64) {
        bool act = lane < deg;
        int src = 0; float e = -INFINITY;
        if (act) {
            src = col[beg + lane];
            e = lrelu(asrc[src] + ad);
        }
        float m = e;
        #pragma unroll
        for (int off = 32; off; off >>= 1) m = fmaxf(m, __shfl_xor(m, off));
        float p = act ? __expf(e - m) : 0.f;
        float s = p;
        #pragma unroll
        for (int off = 32; off; off >>= 1) s += __shfl_xor(s, off);
        float w = p / s;
        for (int i = 0; i < deg; ++i) {
            float wi = __shfl(w, i);
            int si = __shfl(src, i);
            acc += wi * bf2f(g_bf[(size_t)si * F2 + lane]);
        }
    } else {
        float m = -INFINITY, s = 0.f;
        for (int k = beg + lane; k < end; k += 64) {
            int src = col[k];
            float e = lrelu(asrc[src] + ad);
            float nm = fmaxf(m, e);
            s = s * __expf(m - nm) + __expf(e - nm); m = nm;
        }
        #pragma unroll
        for (int off = 32; off; off >>= 1) {
            float om = __shfl_xor(m, off), os = __shfl_xor(s, off);
            float nm = fmaxf(m, om);
            s = (nm == -INFINITY) ? 0.f : (s * __expf(m - nm) + os * __expf(om - nm));
            m = nm;
        }
        float inv = 1.f / s;
        for (int base = beg; base < end; base += 64) {
            int k = base + lane;
            bool act = k < end;
            int src = 0; float w = 0.f;
            if (act) {
                src = col[k];
                w = __expf(lrelu(asrc[src] + ad) - m) * inv;
            }
            int cnt = min(64, end - base);
            for (int i = 0; i < cnt; ++i) {
                float wi = __shfl(w, i);
                int si = __shfl(src, i);
                acc += wi * bf2f(g_bf[(size_t)si * F2 + lane]);
            }
        }
    }
    out[(size_t)n * F2 + lane] = acc + b2[lane];
}

// ---------------------------------------------------------------- launch
extern "C" void kernel_launch(void* const* d_in, const int* in_sizes, int n_in,
                              void* d_out, int out_size, void* d_ws, size_t ws_size,
                              hipStream_t stream) {
    const float* x      = (const float*)d_in[0];
    const int*   ei     = (const int*)d_in[1];
    const float* W1     = (const float*)d_in[2];
    const float* a_src1 = (const float*)d_in[3];
    const float* a_dst1 = (const float*)d_in[4];
    const float* b1     = (const float*)d_in[5];
    const float* W2     = (const float*)d_in[6];
    const float* a_src2 = (const float*)d_in[7];
    const float* a_dst2 = (const float*)d_in[8];
    const float* b2     = (const float*)d_in[9];
    float* out = (float*)d_out;

    char* ws = (char*)d_ws;
    size_t off = 0;
    auto alloc = [&](size_t bytes) -> void* {
        void* p = ws + off;
        off = (off + bytes + 255) & ~(size_t)255;
        return p;
    };
    unsigned short* h_bf   = (unsigned short*)alloc((size_t)N_NODES * F1 * 2); // 25.6 MB
    unsigned short* h1_bf  = (unsigned short*)alloc((size_t)N_NODES * F1 * 2); // 25.6 MB
    unsigned short* g_bf   = (unsigned short*)alloc((size_t)N_NODES * F2 * 2); // 6.4 MB
    unsigned short* Wt1_bf = (unsigned short*)alloc((size_t)F1 * 256 * 2);
    unsigned short* Wt2_bf = (unsigned short*)alloc((size_t)F2 * 256 * 2);
    float* asrc1  = (float*)alloc((size_t)N_NODES * 2 * 4);
    float* adst1  = (float*)alloc((size_t)N_NODES * 2 * 4);
    float* asrc2  = (float*)alloc((size_t)N_NODES * 4);
    float* adst2  = (float*)alloc((size_t)N_NODES * 4);
    int*   rowptr = (int*)alloc((size_t)(N_NODES + 1) * 4);
    int*   cnt    = (int*)alloc((size_t)N_NODES * 4);
    int*   cursor = (int*)alloc((size_t)N_NODES * 4);
    int*   col    = (int*)alloc((size_t)EN_TOT * 4);

    hipMemsetAsync(cnt, 0, (size_t)N_NODES * 4, stream);
    hipMemsetAsync(cursor, 0, (size_t)N_NODES * 4, stream);

    const int eb = (EN_TOT + 255) / 256;
    count_kernel<<<eb, 256, 0, stream>>>(ei, cnt);
    scan_kernel<<<1, 1024, 0, stream>>>(cnt, rowptr, N_NODES);
    fill_kernel<<<eb, 256, 0, stream>>>(ei, rowptr, cursor, col);

    convWT_kernel<<<(256 * F1 + 255) / 256, 256, 0, stream>>>(W1, Wt1_bf, 256, F1);
    convWT_kernel<<<(256 * F2 + 255) / 256, 256, 0, stream>>>(W2, Wt2_bf, 256, F2);

    const int mb = (N_NODES + 127) / 128;   // 391
    const int nb4 = (N_NODES + 3) / 4;      // 12500

    gemm_bf16<128, 128, 2, 2, true><<<dim3(mb, F1 / 128), 256, 0, stream>>>(
        x, Wt1_bf, h_bf, N_NODES, F1, 256);
    alpha1_kernel<<<nb4, 256, 0, stream>>>(h_bf, a_src1, a_dst1, asrc1, adst1);
    agg1_kernel<<<nb4, 256, 0, stream>>>(h_bf, asrc1, adst1, rowptr, col, b1, h1_bf);

    gemm_bf16<128, 64, 4, 1, false><<<dim3(mb, 1), 256, 0, stream>>>(
        h1_bf, Wt2_bf, g_bf, N_NODES, F2, 256);
    alpha2_kernel<<<nb4, 256, 0, stream>>>(g_bf, a_src2, a_dst2, asrc2, adst2);
    agg2_kernel<<<nb4, 256, 0, stream>>>(g_bf, asrc2, adst2, rowptr, col, b2, out);
}

// Round 4
// 254.408 us; speedup vs baseline: 2.7136x; 1.3439x over previous
//
#include <hip/hip_runtime.h>
#include <cmath>
#include <cstdint>
#include <cstddef>

#define N_NODES 50000
#define N_EDGES 800000
#define EN_TOT  (N_EDGES + N_NODES)   // edges + self loops
#define F1 256                         // HEADS*HID
#define F2 64                          // OUT

typedef __attribute__((ext_vector_type(8))) short short8;
typedef __attribute__((ext_vector_type(4))) float float4v;

__device__ __forceinline__ float bf2f(unsigned short u) {
    return __uint_as_float((unsigned)u << 16);
}
__device__ __forceinline__ unsigned short f2bf(float f) {
    unsigned u = __float_as_uint(f);
    unsigned r = (u + 0x7FFFu + ((u >> 16) & 1u)) >> 16;   // round-nearest-even
    return (unsigned short)r;
}
__device__ __forceinline__ float lrelu(float x) { return x > 0.f ? x : 0.2f * x; }

// ---------------------------------------------------------------- CSR build
__global__ void count_kernel(const int* __restrict__ ei, int* __restrict__ cnt) {
    int e = blockIdx.x * 256 + threadIdx.x;
    if (e >= EN_TOT) return;
    int dst = (e < N_EDGES) ? ei[N_EDGES + e] : (e - N_EDGES);
    atomicAdd(&cnt[dst], 1);
}

// multi-block scan: each block scans 4096 counts into rowptr[idx+1], emits bsum
__global__ void scan1_kernel(const int* __restrict__ cnt, int* __restrict__ rowptr,
                             int* __restrict__ bsum, int n) {
    __shared__ int buf[1024];
    int t = threadIdx.x;
    int base = blockIdx.x * 4096 + t * 4;
    int v0 = (base + 0 < n) ? cnt[base + 0] : 0;
    int v1 = (base + 1 < n) ? cnt[base + 1] : 0;
    int v2 = (base + 2 < n) ? cnt[base + 2] : 0;
    int v3 = (base + 3 < n) ? cnt[base + 3] : 0;
    int s0 = v0, s1 = s0 + v1, s2 = s1 + v2, s3 = s2 + v3;
    buf[t] = s3;
    __syncthreads();
    for (int off = 1; off < 1024; off <<= 1) {
        int x = (t >= off) ? buf[t - off] : 0;
        __syncthreads();
        buf[t] += x;
        __syncthreads();
    }
    int ex = buf[t] - s3;   // exclusive prefix within block
    if (base + 0 < n) rowptr[base + 1] = ex + s0;
    if (base + 1 < n) rowptr[base + 2] = ex + s1;
    if (base + 2 < n) rowptr[base + 3] = ex + s2;
    if (base + 3 < n) rowptr[base + 4] = ex + s3;
    if (t == 1023) bsum[blockIdx.x] = buf[1023];
}

__global__ void scan2_kernel(int* __restrict__ rowptr, const int* __restrict__ bsum, int n) {
    __shared__ int soff;
    int b = blockIdx.x, t = threadIdx.x;
    if (t == 0) {
        int o = 0;
        for (int i = 0; i < b; ++i) o += bsum[i];
        soff = o;
    }
    __syncthreads();
    int base = b * 4096 + t * 4;
    #pragma unroll
    for (int j = 0; j < 4; ++j) {
        int idx = base + j;
        if (idx < n) rowptr[idx + 1] += soff;
    }
    if (b == 0 && t == 0) rowptr[0] = 0;
}

__global__ void fill_kernel(const int* __restrict__ ei, const int* __restrict__ rowptr,
                            int* __restrict__ cursor, int* __restrict__ col) {
    int e = blockIdx.x * 256 + threadIdx.x;
    if (e >= EN_TOT) return;
    int src, dst;
    if (e < N_EDGES) { src = ei[e]; dst = ei[N_EDGES + e]; }
    else             { src = dst = e - N_EDGES; }
    int pos = atomicAdd(&cursor[dst], 1);
    col[rowptr[dst] + pos] = src;
}

// --------------------------------------------- W -> W^T bf16 (tiny matrices)
__global__ void convWT_kernel(const float* __restrict__ W, unsigned short* __restrict__ Wt,
                              int K, int Nw) {
    int idx = blockIdx.x * 256 + threadIdx.x;
    if (idx >= K * Nw) return;
    int n = idx / K, k = idx % K;
    Wt[idx] = f2bf(W[(size_t)k * Nw + n]);
}

// ------------------------------------------- GEMM1 + fused alpha1 epilogue
// C_bf16[M,256] = f32 A[M,256] @ Wt1^T; blockIdx.y == head (cols head*128..+127).
// 4 waves, wave owns 32 rows x all 128 block cols -> in-wave alpha reduction.
__global__ __launch_bounds__(256)
void gemm1_kernel(const float* __restrict__ A, const unsigned short* __restrict__ Bt,
                  unsigned short* __restrict__ Cbf,
                  const float* __restrict__ a_src, const float* __restrict__ a_dst,
                  float* __restrict__ asrc, float* __restrict__ adst, int M) {
    constexpr int BM = 128, BN = 128, BK = 64, K = 256;
    constexpr int FM = 2, FN = 8;
    __shared__ short As[BM * BK];
    __shared__ short Bs[BN * BK];
    const int tid = threadIdx.x;
    const int lane = tid & 63, wid = tid >> 6;
    const int RW = wid * 32;
    const int head = blockIdx.y;
    const int brow = blockIdx.x * BM, bcol = head * BN;
    const int lr = lane & 15, lkg = lane >> 4;

    float4v acc[FM][FN];
    #pragma unroll
    for (int m = 0; m < FM; ++m)
        #pragma unroll
        for (int n = 0; n < FN; ++n) acc[m][n] = (float4v){0.f, 0.f, 0.f, 0.f};

    for (int k0 = 0; k0 < K; k0 += BK) {
        #pragma unroll
        for (int p = 0; p < BM * BK / 1024; ++p) {
            int flat = (p * 256 + tid) * 4;
            int r = flat / BK, kk = flat % BK;
            int gr = brow + r;
            float4 v = make_float4(0.f, 0.f, 0.f, 0.f);
            if (gr < M) v = *(const float4*)&A[(size_t)gr * K + k0 + kk];
            ushort4 o;
            o.x = f2bf(v.x); o.y = f2bf(v.y); o.z = f2bf(v.z); o.w = f2bf(v.w);
            *(ushort4*)((char*)As + r * (BK * 2) + ((kk * 2) ^ ((r & 7) << 4))) = o;
        }
        #pragma unroll
        for (int p = 0; p < BN * BK / 2048; ++p) {
            int flat = (p * 256 + tid) * 8;
            int r = flat / BK, kk = flat % BK;
            short8 v = *(const short8*)&Bt[(size_t)(bcol + r) * K + k0 + kk];
            *(short8*)((char*)Bs + r * (BK * 2) + ((kk * 2) ^ ((r & 7) << 4))) = v;
        }
        __syncthreads();
        #pragma unroll
        for (int ks = 0; ks < 2; ++ks) {
            short8 af[FM], bfr[FN];
            #pragma unroll
            for (int m = 0; m < FM; ++m) {
                int row = RW + m * 16 + lr;
                af[m] = *(const short8*)((const char*)As + row * (BK * 2) +
                        (((ks * 32 + lkg * 8) * 2) ^ ((row & 7) << 4)));
            }
            #pragma unroll
            for (int n = 0; n < FN; ++n) {
                int row = n * 16 + lr;
                bfr[n] = *(const short8*)((const char*)Bs + row * (BK * 2) +
                        (((ks * 32 + lkg * 8) * 2) ^ ((row & 7) << 4)));
            }
            #pragma unroll
            for (int m = 0; m < FM; ++m)
                #pragma unroll
                for (int n = 0; n < FN; ++n)
                    acc[m][n] = __builtin_amdgcn_mfma_f32_16x16x32_bf16(
                        af[m], bfr[n], acc[m][n], 0, 0, 0);
        }
        __syncthreads();
    }
    // epilogue: store bf16 h + fused alpha (dot over this block's 128 cols = head)
    const float* asv = a_src + head * 128;
    const float* adv = a_dst + head * 128;
    #pragma unroll
    for (int m = 0; m < FM; ++m) {
        #pragma unroll
        for (int j = 0; j < 4; ++j) {
            int row = brow + RW + m * 16 + lkg * 4 + j;
            if (row < M) {
                float ps = 0.f, pd = 0.f;
                #pragma unroll
                for (int n = 0; n < FN; ++n) {
                    float v = acc[m][n][j];
                    int c = n * 16 + lr;
                    Cbf[(size_t)row * F1 + bcol + c] = f2bf(v);
                    ps += v * asv[c];
                    pd += v * adv[c];
                }
                #pragma unroll
                for (int off = 1; off < 16; off <<= 1) {
                    ps += __shfl_xor(ps, off);
                    pd += __shfl_xor(pd, off);
                }
                if (lr == 0) {
                    asrc[row * 2 + head] = ps;
                    adst[row * 2 + head] = pd;
                }
            }
        }
    }
}

// ------------------------------------------- GEMM2 + fused alpha2 epilogue
// C_bf16[M,64] = bf16 A[M,256] @ Wt2^T. One block spans all 64 cols.
__global__ __launch_bounds__(256)
void gemm2_kernel(const unsigned short* __restrict__ A, const unsigned short* __restrict__ Bt,
                  unsigned short* __restrict__ Cbf,
                  const float* __restrict__ a_src, const float* __restrict__ a_dst,
                  float* __restrict__ asrc, float* __restrict__ adst, int M) {
    constexpr int BM = 128, BN = 64, BK = 64, K = 256;
    constexpr int FM = 2, FN = 4;
    __shared__ short As[BM * BK];
    __shared__ short Bs[BN * BK];
    const int tid = threadIdx.x;
    const int lane = tid & 63, wid = tid >> 6;
    const int RW = wid * 32;
    const int brow = blockIdx.x * BM;
    const int lr = lane & 15, lkg = lane >> 4;

    float4v acc[FM][FN];
    #pragma unroll
    for (int m = 0; m < FM; ++m)
        #pragma unroll
        for (int n = 0; n < FN; ++n) acc[m][n] = (float4v){0.f, 0.f, 0.f, 0.f};

    for (int k0 = 0; k0 < K; k0 += BK) {
        #pragma unroll
        for (int p = 0; p < BM * BK / 2048; ++p) {
            int flat = (p * 256 + tid) * 8;
            int r = flat / BK, kk = flat % BK;
            int gr = brow + r;
            short8 v = {0, 0, 0, 0, 0, 0, 0, 0};
            if (gr < M) v = *(const short8*)&A[(size_t)gr * K + k0 + kk];
            *(short8*)((char*)As + r * (BK * 2) + ((kk * 2) ^ ((r & 7) << 4))) = v;
        }
        #pragma unroll
        for (int p = 0; p < BN * BK / 2048; ++p) {
            int flat = (p * 256 + tid) * 8;
            int r = flat / BK, kk = flat % BK;
            short8 v = *(const short8*)&Bt[(size_t)r * K + k0 + kk];
            *(short8*)((char*)Bs + r * (BK * 2) + ((kk * 2) ^ ((r & 7) << 4))) = v;
        }
        __syncthreads();
        #pragma unroll
        for (int ks = 0; ks < 2; ++ks) {
            short8 af[FM], bfr[FN];
            #pragma unroll
            for (int m = 0; m < FM; ++m) {
                int row = RW + m * 16 + lr;
                af[m] = *(const short8*)((const char*)As + row * (BK * 2) +
                        (((ks * 32 + lkg * 8) * 2) ^ ((row & 7) << 4)));
            }
            #pragma unroll
            for (int n = 0; n < FN; ++n) {
                int row = n * 16 + lr;
                bfr[n] = *(const short8*)((const char*)Bs + row * (BK * 2) +
                        (((ks * 32 + lkg * 8) * 2) ^ ((row & 7) << 4)));
            }
            #pragma unroll
            for (int m = 0; m < FM; ++m)
                #pragma unroll
                for (int n = 0; n < FN; ++n)
                    acc[m][n] = __builtin_amdgcn_mfma_f32_16x16x32_bf16(
                        af[m], bfr[n], acc[m][n], 0, 0, 0);
        }
        __syncthreads();
    }
    #pragma unroll
    for (int m = 0; m < FM; ++m) {
        #pragma unroll
        for (int j = 0; j < 4; ++j) {
            int row = brow + RW + m * 16 + lkg * 4 + j;
            if (row < M) {
                float ps = 0.f, pd = 0.f;
                #pragma unroll
                for (int n = 0; n < FN; ++n) {
                    float v = acc[m][n][j];
                    int c = n * 16 + lr;
                    Cbf[(size_t)row * F2 + c] = f2bf(v);
                    ps += v * a_src[c];
                    pd += v * a_dst[c];
                }
                #pragma unroll
                for (int off = 1; off < 16; off <<= 1) {
                    ps += __shfl_xor(ps, off);
                    pd += __shfl_xor(pd, off);
                }
                if (lr == 0) {
                    asrc[row] = ps;
                    adst[row] = pd;
                }
            }
        }
    }
}

// ---------------------------------------------------- layer-1 aggregation
// one WAVE per node (4 nodes/block, no barriers). lane owns feats 4*lane..+3.
__global__ __launch_bounds__(256)
void agg1_kernel(const unsigned short* __restrict__ h_bf,
                 const float* __restrict__ asrc, const float* __restrict__ adst,
                 const int* __restrict__ rowptr, const int* __restrict__ col,
                 const float* __restrict__ b1, unsigned short* __restrict__ h1_bf) {
    int n = blockIdx.x * 4 + (threadIdx.x >> 6);
    if (n >= N_NODES) return;
    int lane = threadIdx.x & 63;
    int beg = rowptr[n], end = rowptr[n + 1];
    int deg = end - beg;
    float ad0 = adst[2 * n], ad1 = adst[2 * n + 1];
    float a0 = 0.f, a1 = 0.f, a2 = 0.f, a3 = 0.f;

    if (deg <= 64) {
        bool act = lane < deg;
        int src = 0; float e0 = -INFINITY, e1 = -INFINITY;
        if (act) {
            src = col[beg + lane];
            float2 av = *(const float2*)(asrc + 2 * src);
            e0 = lrelu(av.x + ad0); e1 = lrelu(av.y + ad1);
        }
        float m0 = e0, m1 = e1;
        #pragma unroll
        for (int off = 32; off; off >>= 1) {
            m0 = fmaxf(m0, __shfl_xor(m0, off));
            m1 = fmaxf(m1, __shfl_xor(m1, off));
        }
        float p0 = act ? __expf(e0 - m0) : 0.f;
        float p1 = act ? __expf(e1 - m1) : 0.f;
        float s0 = p0, s1 = p1;
        #pragma unroll
        for (int off = 32; off; off >>= 1) {
            s0 += __shfl_xor(s0, off);
            s1 += __shfl_xor(s1, off);
        }
        float w0 = p0 / s0, w1 = p1 / s1;
        int i = 0;
        for (; i + 1 < deg; i += 2) {
            float wa0 = __shfl(w0, i),     wb0 = __shfl(w1, i);
            float wa1 = __shfl(w0, i + 1), wb1 = __shfl(w1, i + 1);
            int sA = __shfl(src, i), sB = __shfl(src, i + 1);
            float wA = (lane >= 32) ? wb0 : wa0;
            float wB = (lane >= 32) ? wb1 : wa1;
            ushort4 va = *(const ushort4*)(h_bf + (size_t)sA * F1 + lane * 4);
            ushort4 vb = *(const ushort4*)(h_bf + (size_t)sB * F1 + lane * 4);
            a0 += wA * bf2f(va.x) + wB * bf2f(vb.x);
            a1 += wA * bf2f(va.y) + wB * bf2f(vb.y);
            a2 += wA * bf2f(va.z) + wB * bf2f(vb.z);
            a3 += wA * bf2f(va.w) + wB * bf2f(vb.w);
        }
        if (i < deg) {
            float wa = __shfl(w0, i), wb = __shfl(w1, i);
            int s = __shfl(src, i);
            float w = (lane >= 32) ? wb : wa;
            ushort4 v = *(const ushort4*)(h_bf + (size_t)s * F1 + lane * 4);
            a0 += w * bf2f(v.x); a1 += w * bf2f(v.y);
            a2 += w * bf2f(v.z); a3 += w * bf2f(v.w);
        }
    } else {
        float m0 = -INFINITY, s0 = 0.f, m1 = -INFINITY, s1 = 0.f;
        for (int k = beg + lane; k < end; k += 64) {
            int src = col[k];
            float2 av = *(const float2*)(asrc + 2 * src);
            float e0 = lrelu(av.x + ad0), e1 = lrelu(av.y + ad1);
            float nm = fmaxf(m0, e0); s0 = s0 * __expf(m0 - nm) + __expf(e0 - nm); m0 = nm;
            nm = fmaxf(m1, e1); s1 = s1 * __expf(m1 - nm) + __expf(e1 - nm); m1 = nm;
        }
        #pragma unroll
        for (int off = 32; off; off >>= 1) {
            float om = __shfl_xor(m0, off), os = __shfl_xor(s0, off);
            float nm = fmaxf(m0, om);
            s0 = (nm == -INFINITY) ? 0.f : (s0 * __expf(m0 - nm) + os * __expf(om - nm));
            m0 = nm;
            om = __shfl_xor(m1, off); os = __shfl_xor(s1, off);
            nm = fmaxf(m1, om);
            s1 = (nm == -INFINITY) ? 0.f : (s1 * __expf(m1 - nm) + os * __expf(om - nm));
            m1 = nm;
        }
        float i0 = 1.f / s0, i1 = 1.f / s1;
        for (int base = beg; base < end; base += 64) {
            int k = base + lane;
            bool act = k < end;
            int src = 0; float w0 = 0.f, w1 = 0.f;
            if (act) {
                src = col[k];
                float2 av = *(const float2*)(asrc + 2 * src);
                w0 = __expf(lrelu(av.x + ad0) - m0) * i0;
                w1 = __expf(lrelu(av.y + ad1) - m1) * i1;
            }
            int cnt = min(64, end - base);
            for (int i = 0; i < cnt; ++i) {
                float wa = __shfl(w0, i), wb = __shfl(w1, i);
                int s = __shfl(src, i);
                float w = (lane >= 32) ? wb : wa;
                ushort4 v = *(const ushort4*)(h_bf + (size_t)s * F1 + lane * 4);
                a0 += w * bf2f(v.x); a1 += w * bf2f(v.y);
                a2 += w * bf2f(v.z); a3 += w * bf2f(v.w);
            }
        }
    }
    const float4 bb = *(const float4*)(b1 + lane * 4);
    float v0 = a0 + bb.x, v1 = a1 + bb.y, v2 = a2 + bb.z, v3 = a3 + bb.w;
    v0 = v0 > 0.f ? v0 : expm1f(v0);
    v1 = v1 > 0.f ? v1 : expm1f(v1);
    v2 = v2 > 0.f ? v2 : expm1f(v2);
    v3 = v3 > 0.f ? v3 : expm1f(v3);
    ushort4 o; o.x = f2bf(v0); o.y = f2bf(v1); o.z = f2bf(v2); o.w = f2bf(v3);
    *(ushort4*)(h1_bf + (size_t)n * F1 + lane * 4) = o;
}

// ---------------------------------------------------- layer-2 aggregation
// 32-lane group per node (8 nodes / 256-thr block); lane owns feats 2l,2l+1.
__global__ __launch_bounds__(256)
void agg2_kernel(const unsigned short* __restrict__ g_bf,
                 const float* __restrict__ asrc, const float* __restrict__ adst,
                 const int* __restrict__ rowptr, const int* __restrict__ col,
                 const float* __restrict__ b2, float* __restrict__ out) {
    int n = blockIdx.x * 8 + (threadIdx.x >> 5);
    if (n >= N_NODES) return;
    int l = threadIdx.x & 31;
    int lbase = threadIdx.x & 32;        // group offset within wave
    int beg = rowptr[n], end = rowptr[n + 1];
    int deg = end - beg;
    float ad = adst[n];
    float c0 = 0.f, c1 = 0.f;

    if (deg <= 32) {
        bool act = l < deg;
        int src = 0; float e = -INFINITY;
        if (act) {
            src = col[beg + l];
            e = lrelu(asrc[src] + ad);
        }
        float m = e;
        #pragma unroll
        for (int off = 16; off; off >>= 1) m = fmaxf(m, __shfl_xor(m, off));
        float p = act ? __expf(e - m) : 0.f;
        float s = p;
        #pragma unroll
        for (int off = 16; off; off >>= 1) s += __shfl_xor(s, off);
        float w = p / s;
        for (int i = 0; i < deg; ++i) {
            float wi = __shfl(w, lbase + i);
            int si = __shfl(src, lbase + i);
            ushort2 v = *(const ushort2*)(g_bf + (size_t)si * F2 + l * 2);
            c0 += wi * bf2f(v.x);
            c1 += wi * bf2f(v.y);
        }
    } else {
        float m = -INFINITY, s = 0.f;
        for (int k = beg + l; k < end; k += 32) {
            int src = col[k];
            float e = lrelu(asrc[src] + ad);
            float nm = fmaxf(m, e);
            s = s * __expf(m - nm) + __expf(e - nm); m = nm;
        }
        #pragma unroll
        for (int off = 16; off; off >>= 1) {
            float om = __shfl_xor(m, off), os = __shfl_xor(s, off);
            float nm = fmaxf(m, om);
            s = (nm == -INFINITY) ? 0.f : (s * __expf(m - nm) + os * __expf(om - nm));
            m = nm;
        }
        float inv = 1.f / s;
        for (int base = beg; base < end; base += 32) {
            int k = base + l;
            bool act = k < end;
            int src = 0; float w = 0.f;
            if (act) {
                src = col[k];
                w = __expf(lrelu(asrc[src] + ad) - m) * inv;
            }
            int cnt = min(32, end - base);
            for (int i = 0; i < cnt; ++i) {
                float wi = __shfl(w, lbase + i);
                int si = __shfl(src, lbase + i);
                ushort2 v = *(const ushort2*)(g_bf + (size_t)si * F2 + l * 2);
                c0 += wi * bf2f(v.x);
                c1 += wi * bf2f(v.y);
            }
        }
    }
    float2 bb = *(const float2*)(b2 + l * 2);
    float2 o; o.x = c0 + bb.x; o.y = c1 + bb.y;
    *(float2*)&out[(size_t)n * F2 + l * 2] = o;
}

// ---------------------------------------------------------------- launch
extern "C" void kernel_launch(void* const* d_in, const int* in_sizes, int n_in,
                              void* d_out, int out_size, void* d_ws, size_t ws_size,
                              hipStream_t stream) {
    const float* x      = (const float*)d_in[0];
    const int*   ei     = (const int*)d_in[1];
    const float* W1     = (const float*)d_in[2];
    const float* a_src1 = (const float*)d_in[3];
    const float* a_dst1 = (const float*)d_in[4];
    const float* b1     = (const float*)d_in[5];
    const float* W2     = (const float*)d_in[6];
    const float* a_src2 = (const float*)d_in[7];
    const float* a_dst2 = (const float*)d_in[8];
    const float* b2     = (const float*)d_in[9];
    float* out = (float*)d_out;

    char* ws = (char*)d_ws;
    size_t off = 0;
    auto alloc = [&](size_t bytes) -> void* {
        void* p = ws + off;
        off = (off + bytes + 255) & ~(size_t)255;
        return p;
    };
    unsigned short* h_bf   = (unsigned short*)alloc((size_t)N_NODES * F1 * 2); // 25.6 MB
    unsigned short* h1_bf  = (unsigned short*)alloc((size_t)N_NODES * F1 * 2); // 25.6 MB
    unsigned short* g_bf   = (unsigned short*)alloc((size_t)N_NODES * F2 * 2); // 6.4 MB
    unsigned short* Wt1_bf = (unsigned short*)alloc((size_t)F1 * 256 * 2);
    unsigned short* Wt2_bf = (unsigned short*)alloc((size_t)F2 * 256 * 2);
    float* asrc1  = (float*)alloc((size_t)N_NODES * 2 * 4);
    float* adst1  = (float*)alloc((size_t)N_NODES * 2 * 4);
    float* asrc2  = (float*)alloc((size_t)N_NODES * 4);
    float* adst2  = (float*)alloc((size_t)N_NODES * 4);
    int*   rowptr = (int*)alloc((size_t)(N_NODES + 1) * 4);
    int*   cnt    = (int*)alloc((size_t)N_NODES * 4);
    int*   cursor = (int*)alloc((size_t)N_NODES * 4);
    int*   col    = (int*)alloc((size_t)EN_TOT * 4);
    int*   bsum   = (int*)alloc(64 * 4);

    hipMemsetAsync(cnt, 0, (size_t)N_NODES * 4, stream);
    hipMemsetAsync(cursor, 0, (size_t)N_NODES * 4, stream);

    const int eb = (EN_TOT + 255) / 256;
    count_kernel<<<eb, 256, 0, stream>>>(ei, cnt);
    const int sb = (N_NODES + 4095) / 4096;   // 13
    scan1_kernel<<<sb, 1024, 0, stream>>>(cnt, rowptr, bsum, N_NODES);
    scan2_kernel<<<sb, 1024, 0, stream>>>(rowptr, bsum, N_NODES);
    fill_kernel<<<eb, 256, 0, stream>>>(ei, rowptr, cursor, col);

    convWT_kernel<<<(256 * F1 + 255) / 256, 256, 0, stream>>>(W1, Wt1_bf, 256, F1);
    convWT_kernel<<<(256 * F2 + 255) / 256, 256, 0, stream>>>(W2, Wt2_bf, 256, F2);

    const int mb = (N_NODES + 127) / 128;   // 391
    const int nb4 = (N_NODES + 3) / 4;      // 12500
    const int nb8 = (N_NODES + 7) / 8;      // 6250

    gemm1_kernel<<<dim3(mb, 2), 256, 0, stream>>>(x, Wt1_bf, h_bf, a_src1, a_dst1,
                                                  asrc1, adst1, N_NODES);
    agg1_kernel<<<nb4, 256, 0, stream>>>(h_bf, asrc1, adst1, rowptr, col, b1, h1_bf);

    gemm2_kernel<<<mb, 256, 0, stream>>>(h1_bf, Wt2_bf, g_bf, a_src2, a_dst2,
                                         asrc2, adst2, N_NODES);
    agg2_kernel<<<nb8, 256, 0, stream>>>(g_bf, asrc2, adst2, rowptr, col, b2, out);
}

// Round 5
// 245.003 us; speedup vs baseline: 2.8178x; 1.0384x over previous
//
#include <hip/hip_runtime.h>
#include <cmath>
#include <cstdint>
#include <cstddef>

#define N_NODES 50000
#define N_EDGES 800000
#define EN_TOT  (N_EDGES + N_NODES)   // edges + self loops
#define F1 256                         // HEADS*HID
#define F2 64                          // OUT

typedef __attribute__((ext_vector_type(8))) short short8;
typedef __attribute__((ext_vector_type(4))) float float4v;

__device__ __forceinline__ float bf2f(unsigned short u) {
    return __uint_as_float((unsigned)u << 16);
}
__device__ __forceinline__ unsigned short f2bf(float f) {
    unsigned u = __float_as_uint(f);
    unsigned r = (u + 0x7FFFu + ((u >> 16) & 1u)) >> 16;   // round-nearest-even
    return (unsigned short)r;
}
__device__ __forceinline__ float lrelu(float x) { return x > 0.f ? x : 0.2f * x; }

// ---------------------------------------------------------------- CSR build
__global__ void count_kernel(const int* __restrict__ ei, int* __restrict__ cnt) {
    int e = blockIdx.x * 256 + threadIdx.x;
    if (e >= EN_TOT) return;
    int dst = (e < N_EDGES) ? ei[N_EDGES + e] : (e - N_EDGES);
    atomicAdd(&cnt[dst], 1);
}

// multi-block scan: each block scans 4096 counts into rowptr[idx+1], emits bsum
__global__ void scan1_kernel(const int* __restrict__ cnt, int* __restrict__ rowptr,
                             int* __restrict__ bsum, int n) {
    __shared__ int buf[1024];
    int t = threadIdx.x;
    int base = blockIdx.x * 4096 + t * 4;
    int v0 = (base + 0 < n) ? cnt[base + 0] : 0;
    int v1 = (base + 1 < n) ? cnt[base + 1] : 0;
    int v2 = (base + 2 < n) ? cnt[base + 2] : 0;
    int v3 = (base + 3 < n) ? cnt[base + 3] : 0;
    int s0 = v0, s1 = s0 + v1, s2 = s1 + v2, s3 = s2 + v3;
    buf[t] = s3;
    __syncthreads();
    for (int off = 1; off < 1024; off <<= 1) {
        int x = (t >= off) ? buf[t - off] : 0;
        __syncthreads();
        buf[t] += x;
        __syncthreads();
    }
    int ex = buf[t] - s3;   // exclusive prefix within block
    if (base + 0 < n) rowptr[base + 1] = ex + s0;
    if (base + 1 < n) rowptr[base + 2] = ex + s1;
    if (base + 2 < n) rowptr[base + 3] = ex + s2;
    if (base + 3 < n) rowptr[base + 4] = ex + s3;
    if (t == 1023) bsum[blockIdx.x] = buf[1023];
}

__global__ void scan2_kernel(int* __restrict__ rowptr, const int* __restrict__ bsum, int n) {
    __shared__ int soff;
    int b = blockIdx.x, t = threadIdx.x;
    if (t == 0) {
        int o = 0;
        for (int i = 0; i < b; ++i) o += bsum[i];
        soff = o;
    }
    __syncthreads();
    int base = b * 4096 + t * 4;
    #pragma unroll
    for (int j = 0; j < 4; ++j) {
        int idx = base + j;
        if (idx < n) rowptr[idx + 1] += soff;
    }
    if (b == 0 && t == 0) rowptr[0] = 0;
}

__global__ void fill_kernel(const int* __restrict__ ei, const int* __restrict__ rowptr,
                            int* __restrict__ cursor, int* __restrict__ col) {
    int e = blockIdx.x * 256 + threadIdx.x;
    if (e >= EN_TOT) return;
    int src, dst;
    if (e < N_EDGES) { src = ei[e]; dst = ei[N_EDGES + e]; }
    else             { src = dst = e - N_EDGES; }
    int pos = atomicAdd(&cursor[dst], 1);
    col[rowptr[dst] + pos] = src;
}

// ------------------------------- W1,W2 -> W^T bf16 in one kernel
__global__ void convWT_kernel(const float* __restrict__ W1, const float* __restrict__ W2,
                              unsigned short* __restrict__ Wt1, unsigned short* __restrict__ Wt2) {
    int idx = blockIdx.x * 256 + threadIdx.x;
    if (idx < 256 * F1) {
        int n = idx / 256, k = idx % 256;
        Wt1[idx] = f2bf(W1[(size_t)k * F1 + n]);
    } else {
        int j = idx - 256 * F1;
        if (j < 256 * F2) {
            int n = j / 256, k = j % 256;
            Wt2[j] = f2bf(W2[(size_t)k * F2 + n]);
        }
    }
}

// ------------------------------------------- GEMM1 + fused alpha1 epilogue
// C_bf16[M,256] = f32 A[M,256] @ Wt1^T; blockIdx.y == head (cols head*128..+127).
// 4 waves, wave owns 32 rows x all 128 block cols -> in-wave alpha reduction.
__global__ __launch_bounds__(256)
void gemm1_kernel(const float* __restrict__ A, const unsigned short* __restrict__ Bt,
                  unsigned short* __restrict__ Cbf,
                  const float* __restrict__ a_src, const float* __restrict__ a_dst,
                  float* __restrict__ asrc, float* __restrict__ adst, int M) {
    constexpr int BM = 128, BN = 128, BK = 64, K = 256;
    constexpr int FM = 2, FN = 8;
    __shared__ short As[BM * BK];
    __shared__ short Bs[BN * BK];
    const int tid = threadIdx.x;
    const int lane = tid & 63, wid = tid >> 6;
    const int RW = wid * 32;
    const int head = blockIdx.y;
    const int brow = blockIdx.x * BM, bcol = head * BN;
    const int lr = lane & 15, lkg = lane >> 4;

    float4v acc[FM][FN];
    #pragma unroll
    for (int m = 0; m < FM; ++m)
        #pragma unroll
        for (int n = 0; n < FN; ++n) acc[m][n] = (float4v){0.f, 0.f, 0.f, 0.f};

    for (int k0 = 0; k0 < K; k0 += BK) {
        #pragma unroll
        for (int p = 0; p < BM * BK / 1024; ++p) {
            int flat = (p * 256 + tid) * 4;
            int r = flat / BK, kk = flat % BK;
            int gr = brow + r;
            float4 v = make_float4(0.f, 0.f, 0.f, 0.f);
            if (gr < M) v = *(const float4*)&A[(size_t)gr * K + k0 + kk];
            ushort4 o;
            o.x = f2bf(v.x); o.y = f2bf(v.y); o.z = f2bf(v.z); o.w = f2bf(v.w);
            *(ushort4*)((char*)As + r * (BK * 2) + ((kk * 2) ^ ((r & 7) << 4))) = o;
        }
        #pragma unroll
        for (int p = 0; p < BN * BK / 2048; ++p) {
            int flat = (p * 256 + tid) * 8;
            int r = flat / BK, kk = flat % BK;
            short8 v = *(const short8*)&Bt[(size_t)(bcol + r) * K + k0 + kk];
            *(short8*)((char*)Bs + r * (BK * 2) + ((kk * 2) ^ ((r & 7) << 4))) = v;
        }
        __syncthreads();
        #pragma unroll
        for (int ks = 0; ks < 2; ++ks) {
            short8 af[FM], bfr[FN];
            #pragma unroll
            for (int m = 0; m < FM; ++m) {
                int row = RW + m * 16 + lr;
                af[m] = *(const short8*)((const char*)As + row * (BK * 2) +
                        (((ks * 32 + lkg * 8) * 2) ^ ((row & 7) << 4)));
            }
            #pragma unroll
            for (int n = 0; n < FN; ++n) {
                int row = n * 16 + lr;
                bfr[n] = *(const short8*)((const char*)Bs + row * (BK * 2) +
                        (((ks * 32 + lkg * 8) * 2) ^ ((row & 7) << 4)));
            }
            #pragma unroll
            for (int m = 0; m < FM; ++m)
                #pragma unroll
                for (int n = 0; n < FN; ++n)
                    acc[m][n] = __builtin_amdgcn_mfma_f32_16x16x32_bf16(
                        af[m], bfr[n], acc[m][n], 0, 0, 0);
        }
        __syncthreads();
    }
    // epilogue: store bf16 h + fused alpha (dot over this block's 128 cols = head)
    const float* asv = a_src + head * 128;
    const float* adv = a_dst + head * 128;
    #pragma unroll
    for (int m = 0; m < FM; ++m) {
        #pragma unroll
        for (int j = 0; j < 4; ++j) {
            int row = brow + RW + m * 16 + lkg * 4 + j;
            if (row < M) {
                float ps = 0.f, pd = 0.f;
                #pragma unroll
                for (int n = 0; n < FN; ++n) {
                    float v = acc[m][n][j];
                    int c = n * 16 + lr;
                    Cbf[(size_t)row * F1 + bcol + c] = f2bf(v);
                    ps += v * asv[c];
                    pd += v * adv[c];
                }
                #pragma unroll
                for (int off = 1; off < 16; off <<= 1) {
                    ps += __shfl_xor(ps, off);
                    pd += __shfl_xor(pd, off);
                }
                if (lr == 0) {
                    asrc[row * 2 + head] = ps;
                    adst[row * 2 + head] = pd;
                }
            }
        }
    }
}

// ------------------------------------------- GEMM2 + fused alpha2 epilogue
__global__ __launch_bounds__(256)
void gemm2_kernel(const unsigned short* __restrict__ A, const unsigned short* __restrict__ Bt,
                  unsigned short* __restrict__ Cbf,
                  const float* __restrict__ a_src, const float* __restrict__ a_dst,
                  float* __restrict__ asrc, float* __restrict__ adst, int M) {
    constexpr int BM = 128, BN = 64, BK = 64, K = 256;
    constexpr int FM = 2, FN = 4;
    __shared__ short As[BM * BK];
    __shared__ short Bs[BN * BK];
    const int tid = threadIdx.x;
    const int lane = tid & 63, wid = tid >> 6;
    const int RW = wid * 32;
    const int brow = blockIdx.x * BM;
    const int lr = lane & 15, lkg = lane >> 4;

    float4v acc[FM][FN];
    #pragma unroll
    for (int m = 0; m < FM; ++m)
        #pragma unroll
        for (int n = 0; n < FN; ++n) acc[m][n] = (float4v){0.f, 0.f, 0.f, 0.f};

    for (int k0 = 0; k0 < K; k0 += BK) {
        #pragma unroll
        for (int p = 0; p < BM * BK / 2048; ++p) {
            int flat = (p * 256 + tid) * 8;
            int r = flat / BK, kk = flat % BK;
            int gr = brow + r;
            short8 v = {0, 0, 0, 0, 0, 0, 0, 0};
            if (gr < M) v = *(const short8*)&A[(size_t)gr * K + k0 + kk];
            *(short8*)((char*)As + r * (BK * 2) + ((kk * 2) ^ ((r & 7) << 4))) = v;
        }
        #pragma unroll
        for (int p = 0; p < BN * BK / 2048; ++p) {
            int flat = (p * 256 + tid) * 8;
            int r = flat / BK, kk = flat % BK;
            short8 v = *(const short8*)&Bt[(size_t)r * K + k0 + kk];
            *(short8*)((char*)Bs + r * (BK * 2) + ((kk * 2) ^ ((r & 7) << 4))) = v;
        }
        __syncthreads();
        #pragma unroll
        for (int ks = 0; ks < 2; ++ks) {
            short8 af[FM], bfr[FN];
            #pragma unroll
            for (int m = 0; m < FM; ++m) {
                int row = RW + m * 16 + lr;
                af[m] = *(const short8*)((const char*)As + row * (BK * 2) +
                        (((ks * 32 + lkg * 8) * 2) ^ ((row & 7) << 4)));
            }
            #pragma unroll
            for (int n = 0; n < FN; ++n) {
                int row = n * 16 + lr;
                bfr[n] = *(const short8*)((const char*)Bs + row * (BK * 2) +
                        (((ks * 32 + lkg * 8) * 2) ^ ((row & 7) << 4)));
            }
            #pragma unroll
            for (int m = 0; m < FM; ++m)
                #pragma unroll
                for (int n = 0; n < FN; ++n)
                    acc[m][n] = __builtin_amdgcn_mfma_f32_16x16x32_bf16(
                        af[m], bfr[n], acc[m][n], 0, 0, 0);
        }
        __syncthreads();
    }
    #pragma unroll
    for (int m = 0; m < FM; ++m) {
        #pragma unroll
        for (int j = 0; j < 4; ++j) {
            int row = brow + RW + m * 16 + lkg * 4 + j;
            if (row < M) {
                float ps = 0.f, pd = 0.f;
                #pragma unroll
                for (int n = 0; n < FN; ++n) {
                    float v = acc[m][n][j];
                    int c = n * 16 + lr;
                    Cbf[(size_t)row * F2 + c] = f2bf(v);
                    ps += v * a_src[c];
                    pd += v * a_dst[c];
                }
                #pragma unroll
                for (int off = 1; off < 16; off <<= 1) {
                    ps += __shfl_xor(ps, off);
                    pd += __shfl_xor(pd, off);
                }
                if (lr == 0) {
                    asrc[row] = ps;
                    adst[row] = pd;
                }
            }
        }
    }
}

// ---------------------------------------------------- layer-1 aggregation
// one WAVE per node (4 nodes/block). fast path: halves of the wave process
// even/odd edges; lane owns 8 feats, loads ushort8 (16B); xor(32) combine.
__global__ __launch_bounds__(256)
void agg1_kernel(const unsigned short* __restrict__ h_bf,
                 const float* __restrict__ asrc, const float* __restrict__ adst,
                 const int* __restrict__ rowptr, const int* __restrict__ col,
                 const float* __restrict__ b1, unsigned short* __restrict__ h1_bf) {
    int n = blockIdx.x * 4 + (threadIdx.x >> 6);
    if (n >= N_NODES) return;
    int lane = threadIdx.x & 63;
    int beg = rowptr[n], end = rowptr[n + 1];
    int deg = end - beg;
    float ad0 = adst[2 * n], ad1 = adst[2 * n + 1];

    if (deg <= 64) {
        bool act = lane < deg;
        int src = 0; float e0 = -INFINITY, e1 = -INFINITY;
        if (act) {
            src = col[beg + lane];
            float2 av = *(const float2*)(asrc + 2 * src);
            e0 = lrelu(av.x + ad0); e1 = lrelu(av.y + ad1);
        }
        float m0 = e0, m1 = e1;
        #pragma unroll
        for (int off = 32; off; off >>= 1) {
            m0 = fmaxf(m0, __shfl_xor(m0, off));
            m1 = fmaxf(m1, __shfl_xor(m1, off));
        }
        float p0 = act ? __expf(e0 - m0) : 0.f;
        float p1 = act ? __expf(e1 - m1) : 0.f;
        float s0 = p0, s1 = p1;
        #pragma unroll
        for (int off = 32; off; off >>= 1) {
            s0 += __shfl_xor(s0, off);
            s1 += __shfl_xor(s1, off);
        }
        float w0 = p0 / s0, w1 = p1 / s1;

        int half = lane >> 5, fl = lane & 31;
        bool myhead = fl >= 16;                 // feats 8*fl..: head1 iff fl>=16
        float a[8] = {0.f, 0.f, 0.f, 0.f, 0.f, 0.f, 0.f, 0.f};
        for (int i = 0; i < deg; i += 2) {
            int ei = i + half;
            bool ok = ei < deg;
            int eidx = ok ? ei : 0;
            float wa = __shfl(w0, eidx), wb = __shfl(w1, eidx);
            int s = __shfl(src, eidx);
            float w = myhead ? wb : wa;
            if (!ok) w = 0.f;
            short8 v = *(const short8*)(h_bf + (size_t)s * F1 + fl * 8);
            #pragma unroll
            for (int j = 0; j < 8; ++j) a[j] += w * bf2f((unsigned short)v[j]);
        }
        #pragma unroll
        for (int j = 0; j < 8; ++j) a[j] += __shfl_xor(a[j], 32);
        if (half == 0) {
            float bb[8];
            *(float4*)&bb[0] = *(const float4*)(b1 + fl * 8);
            *(float4*)&bb[4] = *(const float4*)(b1 + fl * 8 + 4);
            short8 o;
            #pragma unroll
            for (int j = 0; j < 8; ++j) {
                float v = a[j] + bb[j];
                v = v > 0.f ? v : expm1f(v);
                o[j] = (short)f2bf(v);
            }
            *(short8*)(h1_bf + (size_t)n * F1 + fl * 8) = o;
        }
    } else {
        // general path (rare): per-edge 8B loads, lane owns 4 feats
        float a0 = 0.f, a1 = 0.f, a2 = 0.f, a3 = 0.f;
        float m0 = -INFINITY, s0 = 0.f, m1 = -INFINITY, s1 = 0.f;
        for (int k = beg + lane; k < end; k += 64) {
            int src = col[k];
            float2 av = *(const float2*)(asrc + 2 * src);
            float e0 = lrelu(av.x + ad0), e1 = lrelu(av.y + ad1);
            float nm = fmaxf(m0, e0); s0 = s0 * __expf(m0 - nm) + __expf(e0 - nm); m0 = nm;
            nm = fmaxf(m1, e1); s1 = s1 * __expf(m1 - nm) + __expf(e1 - nm); m1 = nm;
        }
        #pragma unroll
        for (int off = 32; off; off >>= 1) {
            float om = __shfl_xor(m0, off), os = __shfl_xor(s0, off);
            float nm = fmaxf(m0, om);
            s0 = (nm == -INFINITY) ? 0.f : (s0 * __expf(m0 - nm) + os * __expf(om - nm));
            m0 = nm;
            om = __shfl_xor(m1, off); os = __shfl_xor(s1, off);
            nm = fmaxf(m1, om);
            s1 = (nm == -INFINITY) ? 0.f : (s1 * __expf(m1 - nm) + os * __expf(om - nm));
            m1 = nm;
        }
        float i0 = 1.f / s0, i1 = 1.f / s1;
        for (int base = beg; base < end; base += 64) {
            int k = base + lane;
            bool act2 = k < end;
            int src = 0; float w0 = 0.f, w1 = 0.f;
            if (act2) {
                src = col[k];
                float2 av = *(const float2*)(asrc + 2 * src);
                w0 = __expf(lrelu(av.x + ad0) - m0) * i0;
                w1 = __expf(lrelu(av.y + ad1) - m1) * i1;
            }
            int cnt = min(64, end - base);
            for (int i = 0; i < cnt; ++i) {
                float wa = __shfl(w0, i), wb = __shfl(w1, i);
                int s = __shfl(src, i);
                float w = (lane >= 32) ? wb : wa;
                ushort4 v = *(const ushort4*)(h_bf + (size_t)s * F1 + lane * 4);
                a0 += w * bf2f(v.x); a1 += w * bf2f(v.y);
                a2 += w * bf2f(v.z); a3 += w * bf2f(v.w);
            }
        }
        const float4 bb = *(const float4*)(b1 + lane * 4);
        float v0 = a0 + bb.x, v1 = a1 + bb.y, v2 = a2 + bb.z, v3 = a3 + bb.w;
        v0 = v0 > 0.f ? v0 : expm1f(v0);
        v1 = v1 > 0.f ? v1 : expm1f(v1);
        v2 = v2 > 0.f ? v2 : expm1f(v2);
        v3 = v3 > 0.f ? v3 : expm1f(v3);
        ushort4 o; o.x = f2bf(v0); o.y = f2bf(v1); o.z = f2bf(v2); o.w = f2bf(v3);
        *(ushort4*)(h1_bf + (size_t)n * F1 + lane * 4) = o;
    }
}

// ---------------------------------------------------- layer-2 aggregation
// 32-lane group per node (8 nodes/block); fast path: 16-lane subgroups
// process even/odd edges, lane owns 4 feats (ushort4), xor(16) combine.
__global__ __launch_bounds__(256)
void agg2_kernel(const unsigned short* __restrict__ g_bf,
                 const float* __restrict__ asrc, const float* __restrict__ adst,
                 const int* __restrict__ rowptr, const int* __restrict__ col,
                 const float* __restrict__ b2, float* __restrict__ out) {
    int n = blockIdx.x * 8 + (threadIdx.x >> 5);
    if (n >= N_NODES) return;
    int l = threadIdx.x & 31;
    int lbase = threadIdx.x & 32;        // group offset within wave
    int beg = rowptr[n], end = rowptr[n + 1];
    int deg = end - beg;
    float ad = adst[n];

    if (deg <= 32) {
        bool act = l < deg;
        int src = 0; float e = -INFINITY;
        if (act) {
            src = col[beg + l];
            e = lrelu(asrc[src] + ad);
        }
        float m = e;
        #pragma unroll
        for (int off = 16; off; off >>= 1) m = fmaxf(m, __shfl_xor(m, off));
        float p = act ? __expf(e - m) : 0.f;
        float s = p;
        #pragma unroll
        for (int off = 16; off; off >>= 1) s += __shfl_xor(s, off);
        float w = p / s;

        int sub = l >> 4, fl = l & 15;
        float a0 = 0.f, a1 = 0.f, a2 = 0.f, a3 = 0.f;
        for (int i = 0; i < deg; i += 2) {
            int ei = i + sub;
            bool ok = ei < deg;
            int eidx = ok ? ei : 0;
            float wi = __shfl(w, lbase + eidx);
            int si = __shfl(src, lbase + eidx);
            if (!ok) wi = 0.f;
            ushort4 v = *(const ushort4*)(g_bf + (size_t)si * F2 + fl * 4);
            a0 += wi * bf2f(v.x); a1 += wi * bf2f(v.y);
            a2 += wi * bf2f(v.z); a3 += wi * bf2f(v.w);
        }
        a0 += __shfl_xor(a0, 16); a1 += __shfl_xor(a1, 16);
        a2 += __shfl_xor(a2, 16); a3 += __shfl_xor(a3, 16);
        if (sub == 0) {
            float4 bb = *(const float4*)(b2 + fl * 4);
            float4 o;
            o.x = a0 + bb.x; o.y = a1 + bb.y; o.z = a2 + bb.z; o.w = a3 + bb.w;
            *(float4*)&out[(size_t)n * F2 + fl * 4] = o;
        }
    } else {
        float c0 = 0.f, c1 = 0.f;
        float m = -INFINITY, s = 0.f;
        for (int k = beg + l; k < end; k += 32) {
            int src = col[k];
            float e = lrelu(asrc[src] + ad);
            float nm = fmaxf(m, e);
            s = s * __expf(m - nm) + __expf(e - nm); m = nm;
        }
        #pragma unroll
        for (int off = 16; off; off >>= 1) {
            float om = __shfl_xor(m, off), os = __shfl_xor(s, off);
            float nm = fmaxf(m, om);
            s = (nm == -INFINITY) ? 0.f : (s * __expf(m - nm) + os * __expf(om - nm));
            m = nm;
        }
        float inv = 1.f / s;
        for (int base = beg; base < end; base += 32) {
            int k = base + l;
            bool act2 = k < end;
            int src = 0; float w = 0.f;
            if (act2) {
                src = col[k];
                w = __expf(lrelu(asrc[src] + ad) - m) * inv;
            }
            int cnt = min(32, end - base);
            for (int i = 0; i < cnt; ++i) {
                float wi = __shfl(w, lbase + i);
                int si = __shfl(src, lbase + i);
                ushort2 v = *(const ushort2*)(g_bf + (size_t)si * F2 + l * 2);
                c0 += wi * bf2f(v.x);
                c1 += wi * bf2f(v.y);
            }
        }
        float2 bb = *(const float2*)(b2 + l * 2);
        float2 o; o.x = c0 + bb.x; o.y = c1 + bb.y;
        *(float2*)&out[(size_t)n * F2 + l * 2] = o;
    }
}

// ---------------------------------------------------------------- launch
extern "C" void kernel_launch(void* const* d_in, const int* in_sizes, int n_in,
                              void* d_out, int out_size, void* d_ws, size_t ws_size,
                              hipStream_t stream) {
    const float* x      = (const float*)d_in[0];
    const int*   ei     = (const int*)d_in[1];
    const float* W1     = (const float*)d_in[2];
    const float* a_src1 = (const float*)d_in[3];
    const float* a_dst1 = (const float*)d_in[4];
    const float* b1     = (const float*)d_in[5];
    const float* W2     = (const float*)d_in[6];
    const float* a_src2 = (const float*)d_in[7];
    const float* a_dst2 = (const float*)d_in[8];
    const float* b2     = (const float*)d_in[9];
    float* out = (float*)d_out;

    char* ws = (char*)d_ws;
    size_t off = 0;
    auto alloc = [&](size_t bytes) -> void* {
        void* p = ws + off;
        off = (off + bytes + 255) & ~(size_t)255;
        return p;
    };
    unsigned short* h_bf   = (unsigned short*)alloc((size_t)N_NODES * F1 * 2); // 25.6 MB
    unsigned short* h1_bf  = (unsigned short*)alloc((size_t)N_NODES * F1 * 2); // 25.6 MB
    unsigned short* g_bf   = (unsigned short*)alloc((size_t)N_NODES * F2 * 2); // 6.4 MB
    unsigned short* Wt1_bf = (unsigned short*)alloc((size_t)F1 * 256 * 2);
    unsigned short* Wt2_bf = (unsigned short*)alloc((size_t)F2 * 256 * 2);
    float* asrc1  = (float*)alloc((size_t)N_NODES * 2 * 4);
    float* adst1  = (float*)alloc((size_t)N_NODES * 2 * 4);
    float* asrc2  = (float*)alloc((size_t)N_NODES * 4);
    float* adst2  = (float*)alloc((size_t)N_NODES * 4);
    int*   rowptr = (int*)alloc((size_t)(N_NODES + 1) * 4);
    int*   cc     = (int*)alloc((size_t)N_NODES * 2 * 4);   // cnt + cursor contiguous
    int*   cnt    = cc;
    int*   cursor = cc + N_NODES;
    int*   col    = (int*)alloc((size_t)EN_TOT * 4);
    int*   bsum   = (int*)alloc(64 * 4);

    hipMemsetAsync(cc, 0, (size_t)N_NODES * 2 * 4, stream);

    const int eb = (EN_TOT + 255) / 256;
    count_kernel<<<eb, 256, 0, stream>>>(ei, cnt);
    const int sb = (N_NODES + 4095) / 4096;   // 13
    scan1_kernel<<<sb, 1024, 0, stream>>>(cnt, rowptr, bsum, N_NODES);
    scan2_kernel<<<sb, 1024, 0, stream>>>(rowptr, bsum, N_NODES);
    fill_kernel<<<eb, 256, 0, stream>>>(ei, rowptr, cursor, col);

    convWT_kernel<<<(256 * (F1 + F2) + 255) / 256, 256, 0, stream>>>(W1, W2, Wt1_bf, Wt2_bf);

    const int mb = (N_NODES + 127) / 128;   // 391
    const int nb4 = (N_NODES + 3) / 4;      // 12500
    const int nb8 = (N_NODES + 7) / 8;      // 6250

    gemm1_kernel<<<dim3(mb, 2), 256, 0, stream>>>(x, Wt1_bf, h_bf, a_src1, a_dst1,
                                                  asrc1, adst1, N_NODES);
    agg1_kernel<<<nb4, 256, 0, stream>>>(h_bf, asrc1, adst1, rowptr, col, b1, h1_bf);

    gemm2_kernel<<<mb, 256, 0, stream>>>(h1_bf, Wt2_bf, g_bf, a_src2, a_dst2,
                                         asrc2, adst2, N_NODES);
    agg2_kernel<<<nb8, 256, 0, stream>>>(g_bf, asrc2, adst2, rowptr, col, b2, out);
}